// Round 9
// baseline (271.530 us; speedup 1.0000x reference)
//
#include <hip/hip_runtime.h>
#include <cstdint>

#define A_NUM 9
#define C_NUM 20
#define B_SZ 32
#define HW 784            // 28*28
#define P_NUM (A_NUM*HW)  // 7056
#define NBOX 64
#define CIN 1280
#define HID 128
#define M_IDX 4096
#define KS_ALL 40         // 1280/32 k-slabs
#define HSTR2 136         // h LDS row stride in bf16 elems
#define OSTR 80           // Hd row stride in floats (65 used, pad to 80)
#define IOU_PB 64         // p-rows per iou block

// output layout (flat concat in return order)
#define CONF_OFF 0
#define OFFS_OFF (2*M_IDX)                 // 8192
#define CLS_OFF  (OFFS_OFF + 4*M_IDX)      // 24576
#define IOU_OFF  (CLS_OFF + C_NUM*M_IDX)   // 106496

#define TRANS_BLKS (B_SZ*KS_ALL)                  // 1280
#define IOU_BX ((P_NUM + IOU_PB - 1)/IOU_PB)      // 111
#define IOU_BLKS (IOU_BX*B_SZ)                    // 3552
#define GEMM_WAVES (B_SZ*49)                      // 1568 (16-row m-frags)

typedef short bf16x8 __attribute__((ext_vector_type(8)));
typedef float f32x4  __attribute__((ext_vector_type(4)));

// round-half-up fp32->bf16, packed pair into one dword
__device__ __forceinline__ unsigned pack_bf16(float lo, float hi) {
  unsigned a = __builtin_bit_cast(unsigned, lo);
  unsigned b = __builtin_bit_cast(unsigned, hi);
  return ((a + 0x8000u) >> 16) | ((b + 0x8000u) & 0xffff0000u);
}

// ---- weight prep: W1 and W2 fp32 -> bf16 MFMA B-fragment order -------------
__global__ __launch_bounds__(256) void prep_w(const float* __restrict__ W1,
                                              const float* __restrict__ W2,
                                              uint4* __restrict__ W1f,
                                              uint4* __restrict__ W2f) {
  int id = blockIdx.x * 256 + threadIdx.x;  // 85*256 = 21760 threads
  if (id < 20480) {
    int lane = id & 63;
    int ntile = (id >> 6) & 7;
    int ks = id >> 9;                       // 0..39
    int lo = lane & 15, quad = lane >> 4;
    int n = ntile * 16 + lo;
    int k0 = ks * 32 + quad * 8;
    const float* src = W1 + n * CIN + k0;
    float4 x = *(const float4*)src;
    float4 y = *(const float4*)(src + 4);
    uint4 p;
    p.x = pack_bf16(x.x, x.y);
    p.y = pack_bf16(x.z, x.w);
    p.z = pack_bf16(y.x, y.y);
    p.w = pack_bf16(y.z, y.w);
    W1f[id] = p;
  } else {
    int i2 = id - 20480;                    // 0..1279
    int lane = i2 & 63;
    int ntile = (i2 >> 6) % 5;
    int ks = i2 / 320;                      // 0..3
    int lo = lane & 15, quad = lane >> 4;
    int n = ntile * 16 + lo;
    int k0 = ks * 32 + quad * 8;
    uint4 p = (uint4){0, 0, 0, 0};
    if (n < 5 * A_NUM + C_NUM) {
      const float* src = W2 + n * HID + k0;
      float4 x = *(const float4*)src;
      float4 y = *(const float4*)(src + 4);
      p.x = pack_bf16(x.x, x.y);
      p.y = pack_bf16(x.z, x.w);
      p.z = pack_bf16(y.x, y.y);
      p.w = pack_bf16(y.z, y.w);
    }
    W2f[i2] = p;
  }
}

// ---- transpose F -> Af (bf16 A-fragment layout) + IoU ----------------------
// Af[b][ks][m] = 64 B = 32 bf16, c = ks*32 .. +31 in order (4 uint4, q-th
// uint4 holds c 8q..8q+7 as 4 packed dwords). GEMM lane (quad,lo) then reads
// one uint4 at ((b*40+ks)*784 + m0+lo)*4 + quad  -> wave-contiguous 1 KB.
union SharedT {
  struct { float tile[32][136]; } t;                     // 17408 B
  struct { float sb[NBOX * 5]; float4 sp4[IOU_PB]; } i;  // 2304 B
};

__global__ __launch_bounds__(256) void trans_iou(
    const float* __restrict__ F, uint4* __restrict__ Af,
    const float* __restrict__ gridc, const float* __restrict__ anc,
    const float* __restrict__ bboxes, float* __restrict__ iou_out) {
  __shared__ SharedT sh;
  const int bid = blockIdx.x;
  const int t = threadIdx.x;

  if (bid < TRANS_BLKS) {
    // ============== transpose: block = (b, ks) slab of 32 c-rows ============
    const int b = bid / KS_ALL, ks = bid - b * KS_ALL;
    const float* Fsrc = F + ((size_t)b * CIN + ks * 32) * HW;
    uint4* Adst = Af + (size_t)(b * KS_ALL + ks) * (HW * 4);
    const int row = t >> 3, s0 = t & 7;   // read roles: 32 rows x 8 lanes
    const int tm = t >> 1, hh = t & 1;    // pack roles: 128 m x 2 halves
    for (int ch = 0; ch < 7; ch++) {
      const int mbase = ch * 128;
      const int W = (ch < 6) ? 128 : 16;  // 6*128 + 16 = 784
#pragma unroll
      for (int i = 0; i < 4; i++) {
        const int slot = s0 + 8 * i;
        if (slot * 4 < W) {
          float4 v = *(const float4*)(Fsrc + (size_t)row * HW + mbase + slot * 4);
          *(float4*)&sh.t.tile[row][slot * 4] = v;
        }
      }
      __syncthreads();
      if (tm < W) {
        const int m = mbase + tm;
        unsigned d[8];
#pragma unroll
        for (int j = 0; j < 8; j++)
          d[j] = pack_bf16(sh.t.tile[16 * hh + 2 * j][tm],
                           sh.t.tile[16 * hh + 2 * j + 1][tm]);
        Adst[m * 4 + 2 * hh]     = (uint4){d[0], d[1], d[2], d[3]};
        Adst[m * 4 + 2 * hh + 1] = (uint4){d[4], d[5], d[6], d[7]};
      }
      __syncthreads();
    }
    return;
  }

  // ================= IoU part (unchanged math) =================
  const int bid2 = bid - TRANS_BLKS;
  const int b = bid2 / IOU_BX;
  const int p0 = (bid2 - b * IOU_BX) * IOU_PB;
  float* sb = sh.i.sb;
  float4* sp4 = sh.i.sp4;
  for (int i = t; i < NBOX * 5; i += 256) sb[i] = bboxes[b * NBOX * 5 + i];
  if (t < IOU_PB) {
    int p = p0 + t;
    float x1 = 0.f, y1 = 0.f, x2 = 0.f, y2 = 0.f;
    if (p < P_NUM) {
      int a = p / HW, hw = p - a * HW;
      float2 c = ((const float2*)gridc)[b * HW + hw];
      float hx = anc[a * 2 + 0] * 0.5f, hy = anc[a * 2 + 1] * 0.5f;
      x1 = c.x - hx; y1 = c.y - hy; x2 = c.x + hx; y2 = c.y + hy;
    }
    sp4[t] = make_float4(x1, y1, x2, y2);
  }
  __syncthreads();
  const int nl = (t & 15) * 4;
  const int pi = t >> 4;
#pragma unroll
  for (int ip = 0; ip < 4; ip++) {
    const int pl = pi + 16 * ip;
    const int p = p0 + pl;
    const float4 pb = sp4[pl];
    const float spA = (pb.z - pb.x) * (pb.w - pb.y);
    float4 res;
#pragma unroll
    for (int jn = 0; jn < 4; jn++) {
      const int n = nl + jn;
      float bx1 = sb[n * 5 + 0], by1 = sb[n * 5 + 1];
      float bx2 = sb[n * 5 + 2], by2 = sb[n * 5 + 3];
      float s_b = (bx2 - bx1) * (by2 - by1);
      float ix1 = fmaxf(pb.x, bx1), iy1 = fmaxf(pb.y, by1);
      float ix2 = fminf(pb.z, bx2), iy2 = fminf(pb.w, by2);
      float si = fmaxf(ix2 - ix1, 0.f) * fmaxf(iy2 - iy1, 0.f);
      float su = spA + s_b - si;
      float iou = fmaxf(si / (su + 1e-8f), 0.f);
      bool invalid = (su <= 0.f) | (spA <= 0.f) | (s_b <= 0.f) | (bx1 < 0.f);
      float v = invalid ? 0.f : iou;
      if (jn == 0) res.x = v; else if (jn == 1) res.y = v;
      else if (jn == 2) res.z = v; else res.w = v;
    }
    if (p < P_NUM)
      *(float4*)&iou_out[((size_t)(b * P_NUM + p)) * 64 + nl] = res;
  }
}

// ---- GEMM: 1568 single-wave blocks, 16m x 128n, barrier-free, linear A -----
__global__ __launch_bounds__(64) void gemm_head(
    const uint4* __restrict__ Af, const uint4* __restrict__ W1f,
    const uint4* __restrict__ W2f, const float* __restrict__ b1,
    const float* __restrict__ b2, float* __restrict__ Hd) {
  __shared__ unsigned short h[16 * HSTR2];
  const int g = blockIdx.x;
  const int b = g / 49, mf = g - b * 49;
  const int m0 = mf * 16;
  const int lane = threadIdx.x & 63, quad = lane >> 4, lo = lane & 15;

  const uint4* Aw = Af + (size_t)(b * KS_ALL) * (HW * 4) + (m0 + lo) * 4 + quad;
  const uint4* Bw = W1f + lane;

  f32x4 acc[8];
#pragma unroll
  for (int i = 0; i < 8; i++) acc[i] = (f32x4){0.f, 0.f, 0.f, 0.f};

  uint4 a[4];        // A frag prefetch depth 4 (rotating)
  uint4 vb[2][8];    // B frag double-buffer

  auto loadB = [&](int s, uint4* dst) {
#pragma unroll
    for (int nt = 0; nt < 8; nt++) dst[nt] = Bw[(size_t)(s * 8 + nt) * 64];
  };

  loadB(0, vb[0]);
#pragma unroll
  for (int i = 0; i < 4; i++) a[i] = Aw[(size_t)i * (HW * 4)];

#pragma unroll
  for (int s = 0; s < KS_ALL; s++) {
    // r8 bugfix: (s+4)&3 aliases s&3 -> copy current A-frag OUT of the
    // rotation register BEFORE issuing the depth-4 prefetch into that slot.
    bf16x8 av = __builtin_bit_cast(bf16x8, a[s & 3]);
    if (s + 1 < KS_ALL) loadB(s + 1, vb[(s + 1) & 1]);
    if (s + 4 < KS_ALL) a[(s + 4) & 3] = Aw[(size_t)(s + 4) * (HW * 4)];
#pragma unroll
    for (int nt = 0; nt < 8; nt++)
      acc[nt] = __builtin_amdgcn_mfma_f32_16x16x32_bf16(
          av, __builtin_bit_cast(bf16x8, vb[s & 1][nt]), acc[nt], 0, 0, 0);
  }

  // ---- h = leakyrelu(acc + b1) -> bf16 LDS tile (this wave only) ----------
#pragma unroll
  for (int nt = 0; nt < 8; nt++) {
    const float bb = b1[nt * 16 + lo];
#pragma unroll
    for (int r = 0; r < 4; r++) {
      float v = acc[nt][r] + bb;
      v = v > 0.f ? v : 0.01f * v;
      unsigned u = __builtin_bit_cast(unsigned, v);
      h[(quad * 4 + r) * HSTR2 + nt * 16 + lo] =
          (unsigned short)((u + 0x8000u) >> 16);
    }
  }
  __syncthreads();

  // ---- W2 head: 5 ntiles, serial in-wave ----------------------------------
#pragma unroll
  for (int nt = 0; nt < 5; nt++) {
    f32x4 a2 = (f32x4){0.f, 0.f, 0.f, 0.f};
#pragma unroll
    for (int k2 = 0; k2 < 4; k2++) {
      bf16x8 haf = *(const bf16x8*)&h[lo * HSTR2 + k2 * 32 + quad * 8];
      bf16x8 bf = __builtin_bit_cast(bf16x8, W2f[(k2 * 5 + nt) * 64 + lane]);
      a2 = __builtin_amdgcn_mfma_f32_16x16x32_bf16(haf, bf, a2, 0, 0, 0);
    }
    const int o = nt * 16 + lo;
    if (o < 5 * A_NUM + C_NUM) {
      const float bz = b2[o];
      const int t5 = (o < 5 * A_NUM) ? (o % 5) : 5;
      const int mrow = m0 + quad * 4;
#pragma unroll
      for (int r = 0; r < 4; r++) {
        const int m = mrow + r;   // 49*16 = 784: always < HW
        float v = a2[r] + bz;
        if (t5 == 0) v = 1.f / (1.f + expf(-v));
        else if (t5 == 1 || t5 == 2) v = 1.f / (1.f + expf(-v)) - 0.5f;
        Hd[((size_t)b * HW + m) * OSTR + o] = v;
      }
    }
  }
}

// ---- gather: pure row copy from activated Hd -------------------------------
__global__ __launch_bounds__(256) void gather2(
    const int* __restrict__ pos_idx, const int* __restrict__ neg_idx,
    const float* __restrict__ Hd, float* __restrict__ out) {
  const int bid = blockIdx.x;
  if (bid < M_IDX / 8) {            // 512 blocks: 8 pos indices each
    const int g = threadIdx.x >> 5; // 32 lanes per index
    const int l = threadIdx.x & 31;
    const int slot = bid * 8 + g;
    const int idx = pos_idx[slot];
    const int b = idx / P_NUM, r = idx - b * P_NUM;
    const int a = r / HW, hw = r - a * HW;
    const float* row = Hd + ((size_t)b * HW + hw) * OSTR;
    if (l == 0)       out[CONF_OFF + slot] = row[a * 5];
    else if (l < 5)   out[OFFS_OFF + slot * 4 + (l - 1)] = row[a * 5 + l];
    else if (l < 25)  out[CLS_OFF + slot * C_NUM + (l - 5)] = row[5 * A_NUM + (l - 5)];
  } else {                          // 16 blocks: 1 neg index per thread
    const int tt = (bid - M_IDX / 8) * 256 + threadIdx.x;
    if (tt < M_IDX) {
      const int idx = neg_idx[tt];
      const int b = idx / P_NUM, r = idx - b * P_NUM;
      const int a = r / HW, hw = r - a * HW;
      out[CONF_OFF + M_IDX + tt] = Hd[((size_t)b * HW + hw) * OSTR + a * 5];
    }
  }
}

extern "C" void kernel_launch(void* const* d_in, const int* in_sizes, int n_in,
                              void* d_out, int out_size, void* d_ws, size_t ws_size,
                              hipStream_t stream) {
  const float* features = (const float*)d_in[0];
  const float* gridc    = (const float*)d_in[1];
  const float* anc      = (const float*)d_in[2];
  const float* bboxes   = (const float*)d_in[3];
  const int*   pos_idx  = (const int*)d_in[4];
  const int*   neg_idx  = (const int*)d_in[5];
  const float* W1       = (const float*)d_in[6];
  const float* b1       = (const float*)d_in[7];
  const float* W2       = (const float*)d_in[8];
  const float* b2       = (const float*)d_in[9];
  float* out = (float*)d_out;

  // ws: W1f 327680 | W2f 20480 | Af 32*40*784*64 = 64225280 | Hd 8028160
  uint4* W1f = (uint4*)d_ws;
  uint4* W2f = (uint4*)((char*)d_ws + 327680);
  uint4* Af  = (uint4*)((char*)d_ws + 348160);
  float* Hd  = (float*)((char*)d_ws + 348160 + 64225280);

  hipLaunchKernelGGL(prep_w, dim3(85), dim3(256), 0, stream, W1, W2, W1f, W2f);
  hipLaunchKernelGGL(trans_iou, dim3(TRANS_BLKS + IOU_BLKS), dim3(256), 0, stream,
                     features, Af, gridc, anc, bboxes, out + IOU_OFF);
  hipLaunchKernelGGL(gemm_head, dim3(GEMM_WAVES), dim3(64), 0, stream,
                     Af, W1f, W2f, b1, b2, Hd);
  hipLaunchKernelGGL(gather2, dim3(M_IDX / 8 + 16), dim3(256), 0, stream,
                     pos_idx, neg_idx, Hd, out);
}